// Round 1
// baseline (297.737 us; speedup 1.0000x reference)
//
#include <hip/hip_runtime.h>
#include <math.h>

#define MAXN 0.996f  /* (1-PROJ_EPS)/sqrt(c) */

__device__ __forceinline__ float wredsum(float v) {
#pragma unroll
  for (int o = 32; o > 0; o >>= 1) v += __shfl_xor(v, o);
  return v;
}

__device__ __forceinline__ float artanh_f(float x) {
  x = fminf(fmaxf(x, -1.0f + 1e-7f), 1.0f - 1e-7f);
  return 0.5f * (log1pf(x) - log1pf(-x));
}

// HypAgg+HypAct+logmap0 nonlinear chain applied to one aggregated row value
__device__ __forceinline__ float chainB(float acc) {
  float n0 = sqrtf(wredsum(acc * acc));
  float u0 = fmaxf(n0, 1e-15f);
  float e1 = tanhf(u0) / u0;
  float c1 = fmaxf(e1 * n0, 1e-15f);
  float v = acc * e1;
  if (c1 > MAXN) { v *= MAXN / c1; c1 = MAXN; }
  v *= artanh_f(c1) / c1;   // logmap0
  v = fmaxf(v, 0.f);        // relu in tangent space
  float n2 = sqrtf(wredsum(v * v));
  float u2 = fmaxf(n2, 1e-15f);
  float e2 = tanhf(u2) / u2;
  float c2 = fmaxf(e2 * n2, 1e-15f);
  v *= e2;
  if (c2 > MAXN) { v *= MAXN / c2; c2 = MAXN; }
  v *= artanh_f(c2) / c2;   // final logmap0
  return v;
}

// per-row sum of x[N,128] -> s[N]; extra 3 blocks transpose W1,W2,W3 for stageA
__global__ void k_rowsumT(const float* __restrict__ x, float* __restrict__ s,
                          const float* __restrict__ W1, const float* __restrict__ W2,
                          const float* __restrict__ W3, float* __restrict__ WT1,
                          float* __restrict__ WT2, float* __restrict__ WT3) {
  const int row = blockIdx.x, j = threadIdx.x;  // 64 threads
  if (row < 8192) {
    float a = x[(size_t)row * 128 + j] + x[(size_t)row * 128 + 64 + j];
    a = wredsum(a);
    if (j == 0) s[row] = a;
    return;
  }
  if (row == 8192) {
    for (int idx = j; idx < 64 * 128; idx += 64) WT1[(idx & 127) * 64 + (idx >> 7)] = W1[idx];
  } else if (row == 8193) {
    for (int idx = j; idx < 64 * 64; idx += 64) WT2[(idx & 63) * 64 + (idx >> 6)] = W2[idx];
  } else {
    for (int idx = j; idx < 64 * 64; idx += 64) WT3[(idx & 63) * 64 + (idx >> 6)] = W3[idx];
  }
}

// scatter edge weights into block-diagonal adj1 [32][256][256]
__global__ void k_edges(const int* __restrict__ er, const int* __restrict__ ec,
                        const float* __restrict__ s, float* __restrict__ adj, int nE) {
  int e = blockIdx.x * blockDim.x + threadIdx.x;
  if (e >= nE) return;
  int r = er[e], c = ec[e];
  int g = r >> 8;
  adj[(((size_t)g * 256) + (r & 255)) * 256 + (c & 255)] = 0.5f * (s[r] + s[c]);
}

// HypLinear + hyperbolic bias + logmap0; one 64-lane wave per row.
// WT is the TRANSPOSED weight [IND][64] so loads are coalesced across lanes.
template <int IND>
__global__ void k_stageA(const float* __restrict__ x, const float* __restrict__ WT,
                         const float* __restrict__ b, float* __restrict__ u) {
  const int row = blockIdx.x;
  const int j = threadIdx.x;  // 64
  __shared__ float xs[IND];
  for (int t = j; t < IND; t += 64) xs[t] = x[(size_t)row * IND + t];
  __syncthreads();

  // hb = proj(expmap0(b))
  float bj = b[j];
  float nb = sqrtf(wredsum(bj * bj));
  float ub = fmaxf(nb, 1e-15f);
  float eb = tanhf(ub) / ub;
  float cb = fmaxf(eb * nb, 1e-15f);
  float hbj = bj * eb * ((cb > MAXN) ? MAXN / cb : 1.0f);
  float y2 = wredsum(hbj * hbj);

  // xh = proj(expmap0(x_row)) = alpha * x_row
  float a2 = 0.f;
  for (int t = j; t < IND; t += 64) a2 += xs[t] * xs[t];
  float nx = sqrtf(wredsum(a2));
  float un = fmaxf(nx, 1e-15f);
  float s1 = tanhf(un) / un;
  float nv = s1 * nx;
  float nn = fmaxf(nv, 1e-15f);
  float s2 = (nn > MAXN) ? MAXN / nn : 1.0f;
  float alpha = s1 * s2;
  float xn = fmaxf(fminf(nn, MAXN), 1e-15f);

  // mx = xh @ W.T  (coalesced: lane j reads WT[t][j])
  float y = 0.f;
  for (int t = 0; t < IND; ++t) y = fmaf(xs[t], WT[t * 64 + j], y);
  float mxj = alpha * y;
  float mxn = fmaxf(sqrtf(wredsum(mxj * mxj)), 1e-15f);
  float hj = (tanhf(mxn / xn * artanh_f(xn)) / mxn) * mxj;

  // proj
  float hn = fmaxf(sqrtf(wredsum(hj * hj)), 1e-15f);
  if (hn > MAXN) hj *= MAXN / hn;

  // mobius_add(h, hb)
  float x2 = wredsum(hj * hj);
  float xy = wredsum(hj * hbj);
  float num = (1.f + 2.f * xy + y2) * hj + (1.f - x2) * hbj;
  float den = fmaxf(1.f + 2.f * xy + x2 * y2, 1e-15f);
  float aj = num / den;

  // proj + logmap0
  float an = fmaxf(sqrtf(wredsum(aj * aj)), 1e-15f);
  float pn = an;
  if (an > MAXN) { aj *= MAXN / an; pn = MAXN; }
  u[(size_t)row * 64 + j] = (artanh_f(pn) / pn) * aj;
}

// HypAgg + HypAct + logmap0 (+ deg->dis).  u-graph staged once in LDS,
// 8 rows per wave register-tiled: 1 ds_read feeds 8 FMAs.
// grid: 32 * (NPGL/32) blocks of 256 threads (4 waves x 8 rows = 32 rows/block)
template <int NPGL>
__global__ void __launch_bounds__(256) k_stageB(const float* __restrict__ adj,
                                                const float* __restrict__ u,
                                                float* __restrict__ t,
                                                float* __restrict__ dis, int wantDis) {
  constexpr int BPG = NPGL / 32;
  const int g = blockIdx.x / BPG;
  const int rbase = (blockIdx.x % BPG) * 32;
  const int tid = threadIdx.x;
  const int w = tid >> 6, j = tid & 63;
  __shared__ float us[NPGL * 64];
  const float* ug = u + (size_t)g * NPGL * 64;
  for (int idx = tid * 4; idx < NPGL * 64; idx += 1024)
    *(float4*)(us + idx) = *(const float4*)(ug + idx);
  __syncthreads();

  const float* adjg = adj + (size_t)g * NPGL * NPGL;
  const float* ar[8];
  float acc[8], dsum[8];
#pragma unroll
  for (int r = 0; r < 8; ++r) {
    ar[r] = adjg + (size_t)(rbase + w * 8 + r) * NPGL;
    acc[r] = 0.f;
    dsum[r] = 0.f;
  }
  for (int c = 0; c < NPGL; ++c) {
    float uv = us[c * 64 + j];
#pragma unroll
    for (int r = 0; r < 8; ++r) {
      float a = ar[r][c];
      acc[r] = fmaf(a, uv, acc[r]);
      dsum[r] += a;
    }
  }
#pragma unroll
  for (int r = 0; r < 8; ++r) {
    const int row = rbase + w * 8 + r;
    float v = chainB(acc[r]);
    t[((size_t)g * NPGL + row) * 64 + j] = v;
    if (wantDis && j == 0)
      dis[(size_t)g * NPGL + row] = (dsum[r] > 0.f) ? (1.0f / sqrtf(dsum[r])) : 0.f;
  }
}

// node info score: score_i = sum_j | t_ij - dis_i * (adj @ (dis.*t))_ij |
// (dis.*t) staged once per graph-slice in LDS; 8 rows/wave register-tiled.
template <int NPGL>
__global__ void __launch_bounds__(256) k_stageC(const float* __restrict__ adj,
                                                const float* __restrict__ t,
                                                const float* __restrict__ dis,
                                                float* __restrict__ score) {
  constexpr int BPG = NPGL / 32;
  const int g = blockIdx.x / BPG;
  const int rbase = (blockIdx.x % BPG) * 32;
  const int tid = threadIdx.x;
  const int w = tid >> 6, j = tid & 63;
  __shared__ float ws[NPGL * 64];
  const float* tg = t + (size_t)g * NPGL * 64;
  const float* dg = dis + (size_t)g * NPGL;
  for (int idx = tid * 4; idx < NPGL * 64; idx += 1024) {
    float4 v = *(const float4*)(tg + idx);
    float dcv = dg[idx >> 6];
    v.x *= dcv; v.y *= dcv; v.z *= dcv; v.w *= dcv;
    *(float4*)(ws + idx) = v;
  }
  __syncthreads();

  const float* adjg = adj + (size_t)g * NPGL * NPGL;
  const float* ar[8];
  float acc[8];
#pragma unroll
  for (int r = 0; r < 8; ++r) {
    ar[r] = adjg + (size_t)(rbase + w * 8 + r) * NPGL;
    acc[r] = 0.f;
  }
  for (int c = 0; c < NPGL; ++c) {
    float uv = ws[c * 64 + j];
#pragma unroll
    for (int r = 0; r < 8; ++r) acc[r] = fmaf(ar[r][c], uv, acc[r]);
  }
#pragma unroll
  for (int r = 0; r < 8; ++r) {
    const int row = rbase + w * 8 + r;
    float d = fabsf(tg[(size_t)row * 64 + j] - dg[row] * acc[r]);
    d = wredsum(d);
    if (j == 0) score[(size_t)g * NPGL + row] = d;
  }
}

// fused top-k select + xn + attention projections + readout + structure-learn adj.
// one block per graph, NPGL threads.
template <int NPGL>
__global__ void k_stageDE(const float* __restrict__ score, const float* __restrict__ t,
                          const float* __restrict__ att, const float* __restrict__ adj_old,
                          float* __restrict__ xn, float* __restrict__ adj_new,
                          float* __restrict__ xread) {
  constexpr int K = NPGL / 2;
  const int g = blockIdx.x;
  const int i = threadIdx.x;  // NPGL threads
  __shared__ float sc[NPGL];
  __shared__ int sel[K];
  __shared__ float sval[K];
  __shared__ float xs[K * 64];
  __shared__ float s1s[K];
  __shared__ float s2s[K];
  sc[i] = score[(size_t)g * NPGL + i];
  __syncthreads();
  float si = sc[i];
  int rank = 0;
  for (int c = 0; c < NPGL; ++c) { float v = sc[c]; rank += (v > si) || (v == si && c < i); }
  if (rank < K) { sel[rank] = i; sval[rank] = si; }
  __syncthreads();
  if (i < K) {
    int li = sel[i];
    float tv = tanhf(sval[i]);
    const float* trow = t + ((size_t)g * NPGL + li) * 64;
    float* xout = xn + ((size_t)g * K + i) * 64;
    float a = 0.f, b = 0.f;
    for (int jj = 0; jj < 64; ++jj) {
      float v = trow[jj] * tv;
      xs[i * 64 + jj] = v;
      a += v * att[jj];
      b += v * att[64 + jj];
      xout[jj] = v;
    }
    s1s[i] = a;
    s2s[i] = b;
  }
  __syncthreads();
  if (i < 64) {
    float mx = -1e30f, sm = 0.f;
    for (int r = 0; r < K; ++r) { float v = xs[r * 64 + i]; mx = fmaxf(mx, v); sm += v; }
    xread[(size_t)g * 128 + i] = mx;
    xread[(size_t)g * 128 + 64 + i] = sm * (1.0f / K);
  }
  // structure learning: new_adj = relu(s1_i + s2_j) + adj_old[sel_i][sel_j]
  const float* aog = adj_old + (size_t)g * NPGL * NPGL;
  float* ang = adj_new + (size_t)g * K * K;
  for (int idx = i; idx < K * K; idx += NPGL) {
    int ii = idx / K, jj = idx - ii * K;
    float e = s1s[ii] + s2s[jj];
    ang[idx] = fmaxf(e, 0.f) + aog[(size_t)sel[ii] * NPGL + sel[jj]];
  }
}

// layer-3 HypAgg chain + readout fused: one block per graph (64 rows),
// 512 threads = 8 waves x 8 rows.
__global__ void __launch_bounds__(512) k_stageB64R(const float* __restrict__ adj,
                                                   const float* __restrict__ u,
                                                   float* __restrict__ xread) {
  const int g = blockIdx.x;
  const int tid = threadIdx.x;  // 512
  const int w = tid >> 6, j = tid & 63;
  __shared__ float us[4096];
  __shared__ float ts[4096];
  const float* ug = u + (size_t)g * 4096;
  for (int idx = tid * 4; idx < 4096; idx += 2048)
    *(float4*)(us + idx) = *(const float4*)(ug + idx);
  __syncthreads();
  const float* adjg = adj + (size_t)g * 4096;
  const int rb = w * 8;
  const float* ar[8];
  float acc[8];
#pragma unroll
  for (int r = 0; r < 8; ++r) {
    ar[r] = adjg + (size_t)(rb + r) * 64;
    acc[r] = 0.f;
  }
  for (int c = 0; c < 64; ++c) {
    float uv = us[c * 64 + j];
#pragma unroll
    for (int r = 0; r < 8; ++r) acc[r] = fmaf(ar[r][c], uv, acc[r]);
  }
#pragma unroll
  for (int r = 0; r < 8; ++r) ts[(rb + r) * 64 + j] = chainB(acc[r]);
  __syncthreads();
  if (tid < 64) {
    float mx = -1e30f, sm = 0.f;
    for (int r = 0; r < 64; ++r) { float v = ts[r * 64 + tid]; mx = fmaxf(mx, v); sm += v; }
    xread[(size_t)g * 128 + tid] = mx;
    xread[(size_t)g * 128 + 64 + tid] = sm * (1.0f / 64.0f);
  }
}

// final MLP head + log_softmax; one block per batch row
__global__ void k_mlp(const float* __restrict__ x1, const float* __restrict__ x2,
                      const float* __restrict__ x3, const float* __restrict__ lw1,
                      const float* __restrict__ lb1, const float* __restrict__ lw2,
                      const float* __restrict__ lb2, const float* __restrict__ lw3,
                      const float* __restrict__ lb3, float* __restrict__ out) {
  const int b = blockIdx.x, j = threadIdx.x;  // 64
  __shared__ float r[128];
  __shared__ float h1[64];
  __shared__ float h2[32];
  __shared__ float z[6];
  for (int t = j; t < 128; t += 64)
    r[t] = fmaxf(x1[(size_t)b * 128 + t], 0.f) + fmaxf(x2[(size_t)b * 128 + t], 0.f) +
           fmaxf(x3[(size_t)b * 128 + t], 0.f);
  __syncthreads();
  float acc = lb1[j];
  for (int t = 0; t < 128; ++t) acc += r[t] * lw1[(size_t)j * 128 + t];
  h1[j] = fmaxf(acc, 0.f);
  __syncthreads();
  if (j < 32) {
    float a = lb2[j];
    for (int t = 0; t < 64; ++t) a += h1[t] * lw2[(size_t)j * 64 + t];
    h2[j] = fmaxf(a, 0.f);
  }
  __syncthreads();
  if (j < 6) {
    float a = lb3[j];
    for (int t = 0; t < 32; ++t) a += h2[t] * lw3[(size_t)j * 32 + t];
    z[j] = a;
  }
  __syncthreads();
  if (j < 6) {
    float m = z[0];
    for (int c = 1; c < 6; ++c) m = fmaxf(m, z[c]);
    float se = 0.f;
    for (int c = 0; c < 6; ++c) se += expf(z[c] - m);
    out[(size_t)b * 6 + j] = z[j] - m - logf(se);
  }
}

extern "C" void kernel_launch(void* const* d_in, const int* in_sizes, int n_in,
                              void* d_out, int out_size, void* d_ws, size_t ws_size,
                              hipStream_t stream) {
  const float* x = (const float*)d_in[0];
  const int* ei = (const int*)d_in[1];
  const float* W1 = (const float*)d_in[2];
  const float* b1 = (const float*)d_in[3];
  const float* W2 = (const float*)d_in[4];
  const float* b2 = (const float*)d_in[5];
  const float* W3 = (const float*)d_in[6];
  const float* b3 = (const float*)d_in[7];
  const float* att1 = (const float*)d_in[8];
  const float* att2 = (const float*)d_in[9];
  const float* lw1 = (const float*)d_in[10];
  const float* lb1 = (const float*)d_in[11];
  const float* lw2 = (const float*)d_in[12];
  const float* lb2 = (const float*)d_in[13];
  const float* lw3 = (const float*)d_in[14];
  const float* lb3 = (const float*)d_in[15];
  float* out = (float*)d_out;
  const int nE = in_sizes[1] / 2;

  float* p = (float*)d_ws;
  float* srow = p;  p += 8192;
  float* adj1 = p;  p += (size_t)32 * 256 * 256;
  float* adj2 = p;  p += (size_t)32 * 128 * 128;
  float* adj3 = p;  p += (size_t)32 * 64 * 64;
  float* ubuf = p;  p += (size_t)8192 * 64;
  float* t1 = p;    p += (size_t)8192 * 64;
  float* t2 = p;    p += (size_t)4096 * 64;
  float* dis = p;   p += 8192;
  float* score = p; p += 8192;
  float* xn1 = p;   p += (size_t)4096 * 64;
  float* xn2 = p;   p += (size_t)2048 * 64;
  float* x1 = p;    p += 32 * 128;
  float* x2 = p;    p += 32 * 128;
  float* x3 = p;    p += 32 * 128;
  float* WT1 = p;   p += 128 * 64;
  float* WT2 = p;   p += 64 * 64;
  float* WT3 = p;   p += 64 * 64;

  hipMemsetAsync(adj1, 0, (size_t)32 * 256 * 256 * sizeof(float), stream);
  k_rowsumT<<<8195, 64, 0, stream>>>(x, srow, W1, W2, W3, WT1, WT2, WT3);
  k_edges<<<(nE + 255) / 256, 256, 0, stream>>>(ei, ei + nE, srow, adj1, nE);

  // layer 1 (N=8192, graph=256)
  k_stageA<128><<<8192, 64, 0, stream>>>(x, WT1, b1, ubuf);
  k_stageB<256><<<256, 256, 0, stream>>>(adj1, ubuf, t1, dis, 1);
  k_stageC<256><<<256, 256, 0, stream>>>(adj1, t1, dis, score);
  k_stageDE<256><<<32, 256, 0, stream>>>(score, t1, att1, adj1, xn1, adj2, x1);

  // layer 2 (N=4096, graph=128)
  k_stageA<64><<<4096, 64, 0, stream>>>(xn1, WT2, b2, ubuf);
  k_stageB<128><<<128, 256, 0, stream>>>(adj2, ubuf, t2, dis, 1);
  k_stageC<128><<<128, 256, 0, stream>>>(adj2, t2, dis, score);
  k_stageDE<128><<<32, 128, 0, stream>>>(score, t2, att2, adj2, xn2, adj3, x2);

  // layer 3 (N=2048, graph=64)
  k_stageA<64><<<2048, 64, 0, stream>>>(xn2, WT3, b3, ubuf);
  k_stageB64R<<<32, 512, 0, stream>>>(adj3, ubuf, x3);

  k_mlp<<<32, 64, 0, stream>>>(x1, x2, x3, lw1, lb1, lw2, lb2, lw3, lb3, out);
}